// Round 23
// baseline (359.915 us; speedup 1.0000x reference)
//
#include <hip/hip_runtime.h>
#include <cstdint>
#include <cstddef>

typedef unsigned short u16;
typedef __attribute__((ext_vector_type(8))) __bf16 bf16x8;
typedef __attribute__((ext_vector_type(4))) unsigned short u16x4;
typedef __attribute__((ext_vector_type(4))) float f32x4;

#define NTOK 197
#define TT   209
#define CDIM 768
#define NH   12
#define HD   64
#define BATCH 64
#define GM (BATCH*TT)   // 13376
#define VTP 224         // padded T stride for transposed V (LDS)
#define NQKV 2304
#define XN (BATCH*NTOK*CDIM)   // 9,682,944 (divisible by 4)

__device__ __forceinline__ float bf2f(u16 u){ return __uint_as_float(((unsigned)u)<<16); }
__device__ __forceinline__ u16 f2bf(float f){
  unsigned x = __float_as_uint(f);
  return (u16)((x + 0x7FFFu + ((x>>16)&1u)) >> 16);   // RNE; inputs finite
}

__device__ __forceinline__ void gll16(const void* g, void* l){
  __builtin_amdgcn_global_load_lds((const __attribute__((address_space(1))) void*)g,
                                   (__attribute__((address_space(3))) void*)l,
                                   16, 0, 0);
}

__device__ __forceinline__ float wsum64(float v){
  #pragma unroll
  for (int o = 32; o > 0; o >>= 1) v += __shfl_xor(v, o, 64);
  return v;
}

// inline dtype detect (prep only): scan x[0:1024] as bf16.
__device__ __forceinline__ int detect_f(const u16* __restrict__ x){
  const int lane = threadIdx.x & 63;
  float mx = 0.f;
  #pragma unroll
  for (int i = 0; i < 16; i++) {
    float v = fabsf(bf2f(x[i*64 + lane]));
    if (!(v < 1e30f)) v = 1e30f;
    mx = fmaxf(mx, v);
  }
  #pragma unroll
  for (int o = 32; o; o >>= 1) mx = fmaxf(mx, __shfl_xor(mx, o, 64));
  return mx < 1e5f;   // 1 = device buffers are bf16
}

__device__ __forceinline__ float ldany(const void* p, size_t i, int f){
  return f ? bf2f(((const u16*)p)[i]) : ((const float*)p)[i];
}

// ---------------------------------------------------------------- prep (fused)
// bid [0,256):    x convert f32->bf16 (skip if bf16)
// bid [256,688):  qkv_w transpose tile (432 tiles)
// bid [688,832):  proj_w transpose tile (144 tiles)
// bid [832,1600): htmm for (b,h): inline 64-col mean, 64x768 matvec, LN+GELU+pos
// bid 1600:       write flag + convert qkv_b -> bf16
// bid 1601:       convert proj_b -> bf16
__global__ __launch_bounds__(256) void prep_kernel(
    const void* __restrict__ xr, const void* __restrict__ w1, const void* __restrict__ w2,
    const void* __restrict__ htw, const void* __restrict__ htb,
    const void* __restrict__ lng, const void* __restrict__ lnb, const void* __restrict__ pos,
    const void* __restrict__ qb_raw, const void* __restrict__ pb_raw,
    u16* __restrict__ xc, u16* __restrict__ o1, u16* __restrict__ o2,
    u16* __restrict__ ht, u16* __restrict__ qbb, u16* __restrict__ pbb,
    int* __restrict__ flagp)
{
  const int tid = threadIdx.x;
  const int f = detect_f((const u16*)xr);
  const int bid = blockIdx.x;
  __shared__ u16 lds[64][66];
  __shared__ float part[4][64];
  __shared__ float msh[64];

  if (bid >= 1600) {                     // ---- flag + bias converts
    if (bid == 1600) {
      if (tid == 0) *flagp = f;
      for (int i = tid; i < NQKV; i += 256) qbb[i] = f2bf(ldany(qb_raw, i, f));
    } else {
      for (int i = tid; i < CDIM; i += 256) pbb[i] = f2bf(ldany(pb_raw, i, f));
    }
    return;
  }
  if (bid < 256) {                       // ---- x convert
    if (f) return;
    const f32x4* in = (const f32x4*)xr;
    const int n4 = XN >> 2;
    for (int i = bid*256 + tid; i < n4; i += 256*256) {
      f32x4 v = in[i];
      u16x4 o;
      #pragma unroll
      for (int j=0;j<4;j++) o[j] = f2bf(v[j]);
      ((u16x4*)xc)[i] = o;
    }
    return;
  }
  if (bid < 832) {                       // ---- weight transposes
    const void* in; u16* out; int N, tx, ty;
    if (bid < 688) { int t = bid-256; in = w1; out = o1; N = NQKV; tx = t % 36; ty = t / 36; }
    else           { int t = bid-688; in = w2; out = o2; N = CDIM; tx = t % 12; ty = t / 12; }
    const int n0 = tx*64, k0 = ty*64;
    const int c = tid & 63, r0 = tid >> 6;
    #pragma unroll
    for (int i=0;i<16;i++) {
      int r = i*4 + r0;
      size_t idx = (size_t)(k0+r)*N + n0 + c;
      lds[r][c] = f ? ((const u16*)in)[idx] : f2bf(((const float*)in)[idx]);
    }
    __syncthreads();
    #pragma unroll
    for (int i=0;i<16;i++) {
      int r = i*4 + r0;
      out[(size_t)(n0+r)*CDIM + k0 + c] = lds[c][r];
    }
    return;
  }

  // ---- htmm: (b,h)
  const int idx = bid - 832;
  const int b = idx / NH, h = idx - b*NH;
  const int c = tid & 63, rg = tid >> 6;
  float s = 0.f;
  for (int n = rg; n < NTOK; n += 4)
    s += ldany(xr, (size_t)(b*NTOK + n)*CDIM + h*HD + c, f);
  part[rg][c] = s;
  __syncthreads();
  if (tid < 64) msh[tid] = (part[0][tid]+part[1][tid]+part[2][tid]+part[3][tid]) * (1.0f/(float)NTOK);
  __syncthreads();

  float v0 = ldany(htb, tid, f), v1 = ldany(htb, tid+256, f), v2 = ldany(htb, tid+512, f);
  for (int d = 0; d < HD; d++) {
    const float md = msh[d];
    const size_t wr = (size_t)d*CDIM;
    v0 += md * ldany(htw, wr + tid, f);
    v1 += md * ldany(htw, wr + tid + 256, f);
    v2 += md * ldany(htw, wr + tid + 512, f);
  }
  const float gam = ldany(lng, tid & 63, f), bet = ldany(lnb, tid & 63, f);
  float vv[3] = {v0, v1, v2};
  #pragma unroll
  for (int ch = 0; ch < 3; ch++) {
    int cc = ch*256 + tid;
    float mu = wsum64(vv[ch]) * (1.0f/(float)HD);
    float dv = vv[ch] - mu;
    float var = wsum64(dv*dv) * (1.0f/(float)HD);
    float y = dv * rsqrtf(var + 1e-5f) * gam + bet;
    float ge = 0.5f * y * (1.0f + erff(y * 0.70710678118654752f));
    float o = ge + ldany(pos, h*CDIM + cc, f);
    ht[((size_t)(b*NH + h))*CDIM + cc] = f2bf(o);
  }
}

// ---------------------------------------------------------------- GEMM
// R21-proven (77µs): flag from memory (uniform SGPR), bf16 bias pointer.
// 128x128 tile, BK=32, 4 waves, ring-5 buffers (80KB), depth-3 prefetch,
// single barrier/iter, counted vmcnt, XOR seg swizzle, m204 XCD remap.
template<int MODE>
__global__ __launch_bounds__(256, 2) void gemm_kernel(
    const u16* __restrict__ A0c, const void* __restrict__ A0r,
    const u16* __restrict__ A1,
    const u16* __restrict__ Bt, const u16* __restrict__ bias,
    u16* __restrict__ qout,
    void* __restrict__ outv, float* __restrict__ csb, const int* __restrict__ flag)
{
  const int tid = threadIdx.x;
  const int lane = tid & 63;
  const int w = tid >> 6;
  const int wm = w >> 1, wn = w & 1;
  const int lr = lane & 15, kg = lane >> 4;

  const int NT = gridDim.x;
  const int nwg = NT * gridDim.y;
  const int orig = blockIdx.y * NT + blockIdx.x;
  const int xcd = orig & 7, sIdx = orig >> 3;
  const int q = nwg >> 3, r = nwg & 7;
  const int wg = ((xcd < r) ? xcd*(q+1) : r*(q+1) + (xcd-r)*q) + sIdx;
  const int tm = wg / NT, tn = wg - tm*NT;

  __shared__ __align__(16) u16 As[5][4096];   // [buf][row*32 + seg*8 + e]
  __shared__ __align__(16) u16 Bs[5][4096];

  const int f = *flag;
  const u16* A0 = (MODE == 0) ? (f ? (const u16*)A0r : A0c) : A0c;

  f32x4 acc[4][4];
  #pragma unroll
  for (int i=0;i<4;i++)
    #pragma unroll
    for (int j=0;j<4;j++) acc[i][j] = (f32x4){0.f,0.f,0.f,0.f};

  const u16* garow[2];
  const u16* gbrow[2];
  #pragma unroll
  for (int i=0;i<2;i++){
    int row = (i*4 + w)*16 + (lane >> 2);
    int rr = tm*128 + row; if (rr > GM-1) rr = GM-1;
    if (MODE == 0) {
      int bb = rr / TT; int t = rr - bb*TT;
      garow[i] = (t < NTOK) ? (A0 + (size_t)(bb*NTOK + t)*CDIM)
                            : (A1 + (size_t)(bb*NH + (t - NTOK))*CDIM);
    } else {
      garow[i] = A0 + (size_t)rr*CDIM;
    }
    gbrow[i] = Bt + (size_t)(tn*128 + row)*CDIM;
  }
  const int gseg = (lane & 3) ^ ((lane >> 3) & 3);   // = seg ^ ((row>>1)&3)

#define STAGE(kt_, bf_) do { \
    const int ko_ = (kt_)*32 + gseg*8; \
    gll16(garow[0] + ko_, (void*)&As[bf_][(0*4+w)*512]); \
    gll16(garow[1] + ko_, (void*)&As[bf_][(1*4+w)*512]); \
    gll16(gbrow[0] + ko_, (void*)&Bs[bf_][(0*4+w)*512]); \
    gll16(gbrow[1] + ko_, (void*)&Bs[bf_][(1*4+w)*512]); \
  } while(0)

  STAGE(0, 0);
  STAGE(1, 1);
  STAGE(2, 2);

  const int spA = kg ^ ((lr >> 1) & 3);   // read-side swizzled segment

  #pragma unroll
  for (int kt = 0; kt < 24; kt++) {
    const int cb = kt % 5;
    if (kt < 21) {
      STAGE(kt+3, (kt+3)%5);
      asm volatile("s_waitcnt vmcnt(12)" ::: "memory");   // stage kt drained
    } else if (kt == 21) {
      asm volatile("s_waitcnt vmcnt(8)" ::: "memory");
    } else if (kt == 22) {
      asm volatile("s_waitcnt vmcnt(4)" ::: "memory");
    } else {
      asm volatile("s_waitcnt vmcnt(0)" ::: "memory");
    }
    __builtin_amdgcn_s_barrier();     // single barrier/iter (ring-5 WAR proof)

    bf16x8 av[4], bv[4];
    #pragma unroll
    for (int mi=0; mi<4; mi++)
      av[mi] = *(const bf16x8*)&As[cb][(wm*64+mi*16+lr)*32 + spA*8];
    #pragma unroll
    for (int ni=0; ni<4; ni++)
      bv[ni] = *(const bf16x8*)&Bs[cb][(wn*64+ni*16+lr)*32 + spA*8];
    #pragma unroll
    for (int mi=0; mi<4; mi++)
      #pragma unroll
      for (int ni=0; ni<4; ni++)
        acc[mi][ni] = __builtin_amdgcn_mfma_f32_16x16x32_bf16(av[mi], bv[ni], acc[mi][ni], 0,0,0);
  }
#undef STAGE

  #pragma unroll
  for (int mi=0; mi<4; mi++){
    const int rb = tm*128 + wm*64 + mi*16 + kg*4;
    #pragma unroll
    for (int ni=0; ni<4; ni++){
      const int c = tn*128 + wn*64 + ni*16 + lr;
      const float bs = bf2f(bias[c]);
      if (MODE == 0) {
        #pragma unroll
        for (int j=0;j<4;j++){
          int rr = rb + j;
          if (rr < GM) qout[(size_t)rr*NQKV + c] = f2bf(acc[mi][ni][j] + bs);
        }
      } else {
        #pragma unroll
        for (int j=0;j<4;j++){
          int rr = rb + j;
          if (rr < GM) {
            int bb = rr / TT; int t = rr - bb*TT;
            float v = acc[mi][ni][j] + bs;
            if (t >= 1 && t < NTOK) {
              size_t oi = ((size_t)(bb*NTOK + t))*CDIM + c;
              if (f) ((u16*)outv)[oi] = f2bf(v);
              else   ((float*)outv)[oi] = v;
            } else {
              int idx = (t == 0) ? 0 : (t - NTOK + 1);   // 0, 1..12
              csb[((size_t)(bb*13 + idx))*CDIM + c] = v;
            }
          }
        }
      }
    }
  }
}

// ---------------------------------------------------------------- attention v4
// One block (8 waves, 512 thr) per (b,h): doubles waves/CU at the same LDS
// footprint (70KB -> 2 blocks/CU = 16 waves/CU vs 8). K staged [224][72];
// V staged transposed [64][232] (zero-pad); one __syncthreads. Per wave:
// q-chunks ck = w, w+8; in-register softmax (swapped QK^T); per-wave 16x32
// P slot written/consumed per ks (wave-local lgkmcnt ordering).
__global__ __launch_bounds__(512, 4) void attn_kernel(
    const u16* __restrict__ qkvo, u16* __restrict__ ob)
{
  __shared__ __align__(16) u16 Kl[224*72];      // 32256 B
  __shared__ __align__(16) u16 Vt[64*232];      // 29696 B
  __shared__ __align__(16) u16 P[8][16*32];     //  8192 B
  const int tid = threadIdx.x;
  const int lane = tid & 63;
  const int w = tid >> 6;                       // 0..7
  const int lr = lane & 15, kg = lane >> 4;

  const int bh = blockIdx.x;
  const int b = bh / NH, h = bh - b*NH;

  const u16* qg   = qkvo + (size_t)(b*TT)*NQKV + h*64;
  const u16* kgp  = qg + CDIM;
  const u16* vsrc = qg + 2*CDIM;

  for (int s = tid; s < 224*8; s += 512) {
    int kc = s >> 3, seg = s & 7;
    uint4 val = make_uint4(0,0,0,0);
    if (kc < TT) val = *(const uint4*)&kgp[(size_t)kc*NQKV + seg*8];
    *(uint4*)&Kl[kc*72 + seg*8] = val;
  }
  for (int s = tid; s < TT*64; s += 512) {
    int t = s >> 6, d = s & 63;
    Vt[d*232 + t] = vsrc[(size_t)t*NQKV + d];
  }
  for (int s = tid; s < 64*(VTP-TT); s += 512) {
    int d = s / (VTP-TT), i = s - d*(VTP-TT);
    Vt[d*232 + TT + i] = 0;
  }
  __syncthreads();

  u16* Pw = &P[w][0];
  for (int ck = w; ck < 14; ck += 8) {
    const int q0 = ck*16;
    int qrow = q0 + lr; if (qrow > TT-1) qrow = TT-1;
    const bf16x8 qf0 = *(const bf16x8*)&qg[(size_t)qrow*NQKV + kg*8];
    const bf16x8 qf1 = *(const bf16x8*)&qg[(size_t)qrow*NQKV + 32 + kg*8];

    f32x4 sv[14];
    #pragma unroll
    for (int kt = 0; kt < 14; kt++) {
      bf16x8 kf0 = *(const bf16x8*)&Kl[(kt*16+lr)*72 + kg*8];
      bf16x8 kf1 = *(const bf16x8*)&Kl[(kt*16+lr)*72 + 32 + kg*8];
      f32x4 sa = {0.f,0.f,0.f,0.f};
      sa = __builtin_amdgcn_mfma_f32_16x16x32_bf16(kf0, qf0, sa, 0,0,0);
      sa = __builtin_amdgcn_mfma_f32_16x16x32_bf16(kf1, qf1, sa, 0,0,0);
      sv[kt] = sa;
    }

    float m = -3.0e38f;
    #pragma unroll
    for (int kt = 0; kt < 13; kt++)
      #pragma unroll
      for (int j=0;j<4;j++){ sv[kt][j] *= 0.125f; m = fmaxf(m, sv[kt][j]); }
    #pragma unroll
    for (int j=0;j<4;j++){
      sv[13][j] *= 0.125f;
      if (208 + kg*4 + j < TT) m = fmaxf(m, sv[13][j]);
    }
    m = fmaxf(m, __shfl_xor(m, 16, 64));
    m = fmaxf(m, __shfl_xor(m, 32, 64));

    float ssum = 0.f;
    #pragma unroll
    for (int kt = 0; kt < 13; kt++)
      #pragma unroll
      for (int j=0;j<4;j++){ float e = __expf(sv[kt][j] - m); sv[kt][j] = e; ssum += e; }
    #pragma unroll
    for (int j=0;j<4;j++){
      float e = (208 + kg*4 + j < TT) ? __expf(sv[13][j] - m) : 0.f;
      sv[13][j] = e; ssum += e;
    }
    ssum += __shfl_xor(ssum, 16, 64);
    ssum += __shfl_xor(ssum, 32, 64);
    const float inv = 1.0f / ssum;

    f32x4 acc[4];
    #pragma unroll
    for (int dt=0; dt<4; dt++) acc[dt] = (f32x4){0.f,0.f,0.f,0.f};
    #pragma unroll
    for (int ks = 0; ks < 7; ks++) {
      u16x4 pk0, pk1;
      #pragma unroll
      for (int j=0;j<4;j++){
        pk0[j] = f2bf(sv[2*ks  ][j] * inv);
        pk1[j] = f2bf(sv[2*ks+1][j] * inv);
      }
      *(u16x4*)&Pw[lr*32      + kg*4] = pk0;
      *(u16x4*)&Pw[lr*32 + 16 + kg*4] = pk1;
      bf16x8 pf = *(const bf16x8*)&Pw[lr*32 + kg*8];
      #pragma unroll
      for (int dt = 0; dt < 4; dt++) {
        bf16x8 vf = *(const bf16x8*)&Vt[(dt*16+lr)*232 + ks*32 + kg*8];
        acc[dt] = __builtin_amdgcn_mfma_f32_16x16x32_bf16(pf, vf, acc[dt], 0,0,0);
      }
    }

    #pragma unroll
    for (int dt = 0; dt < 4; dt++)
      #pragma unroll
      for (int j = 0; j < 4; j++) {
        int tq = q0 + kg*4 + j;
        if (tq < TT)
          ob[((size_t)(b*TT + tq))*CDIM + h*HD + dt*16 + lr] = f2bf(acc[dt][j]);
      }
  }
}

// ---------------------------------------------------------------- final2 (cls row)
__global__ __launch_bounds__(256) void final2_kernel(
    const float* __restrict__ csb, void* __restrict__ outv, const int* __restrict__ flag)
{
  const int f = *flag;
  int i = blockIdx.x*256 + threadIdx.x;
  if (i >= BATCH*CDIM) return;
  int b = i / CDIM, c = i - b*CDIM;
  const float* p = csb + (size_t)b*13*CDIM + c;
  float s = 0.f;
  #pragma unroll
  for (int j = 1; j <= 12; j++) s += p[(size_t)j*CDIM];
  float v = p[0] + s * (1.0f/12.0f);
  size_t oi = ((size_t)b*NTOK)*CDIM + c;
  if (f) ((u16*)outv)[oi] = f2bf(v);
  else   ((float*)outv)[oi] = v;
}

// ---------------------------------------------------------------- launch
extern "C" void kernel_launch(void* const* d_in, const int* in_sizes, int n_in,
                              void* d_out, int out_size, void* d_ws, size_t ws_size,
                              hipStream_t stream)
{
  char* ws = (char*)d_ws;
  size_t off = 0;
  auto alloc = [&](size_t bytes)->void* {
    void* p = ws + off; off += (bytes + 255) & ~(size_t)255; return p;
  };

  int* flag  = (int*)alloc(256);
  u16* qbb   = (u16*)alloc((size_t)NQKV*2);               // bf16 qkv_b
  u16* pbb   = (u16*)alloc((size_t)CDIM*2);               // bf16 proj_b
  u16* xconv = (u16*)alloc((size_t)XN*2);                 // bf16 x (19.4MB)
  u16* qkvT  = (u16*)alloc((size_t)3*CDIM*CDIM*2);        // 2304 x 768 (3.5MB)
  u16* projT = (u16*)alloc((size_t)CDIM*CDIM*2);          // 768 x 768
  u16* htb_  = (u16*)alloc((size_t)BATCH*NH*CDIM*2);      // (B*H) x 768
  u16* qkvo  = (u16*)alloc((size_t)GM*NQKV*2);            // (B*T) x 2304
  float* csb = (float*)alloc((size_t)BATCH*13*CDIM*4);    // cls side buffer
  // ao (20.55MB) aliases xconv+qkvT (22.9MB): both dead after gemm<0>.
  u16* ao    = xconv;

  prep_kernel<<<1602, 256, 0, stream>>>(
      d_in[0], d_in[1], d_in[3], d_in[5], d_in[6], d_in[7], d_in[8], d_in[9],
      d_in[2], d_in[4],
      xconv, qkvT, projT, htb_, qbb, pbb, flag);
  gemm_kernel<0><<<dim3(NQKV/128, (GM+127)/128), 256, 0, stream>>>(
      xconv, d_in[0], htb_, qkvT, qbb, qkvo, nullptr, nullptr, flag);
  attn_kernel<<<BATCH*NH, 512, 0, stream>>>(qkvo, ao);
  gemm_kernel<1><<<dim3(CDIM/128, (GM+127)/128), 256, 0, stream>>>(
      ao, nullptr, nullptr, projT, pbb, nullptr, d_out, csb, flag);
  final2_kernel<<<(BATCH*CDIM+255)/256, 256, 0, stream>>>(csb, d_out, flag);
}

// Round 24
// 211.682 us; speedup vs baseline: 1.7003x; 1.7003x over previous
//
#include <hip/hip_runtime.h>
#include <cstdint>
#include <cstddef>

typedef unsigned short u16;
typedef __attribute__((ext_vector_type(8))) __bf16 bf16x8;
typedef __attribute__((ext_vector_type(4))) unsigned short u16x4;
typedef __attribute__((ext_vector_type(4))) float f32x4;

#define NTOK 197
#define TT   209
#define CDIM 768
#define NH   12
#define HD   64
#define BATCH 64
#define GM (BATCH*TT)   // 13376
#define VTP 224         // padded T stride for transposed V (LDS)
#define NQKV 2304
#define XN (BATCH*NTOK*CDIM)   // 9,682,944 (divisible by 4)

__device__ __forceinline__ float bf2f(u16 u){ return __uint_as_float(((unsigned)u)<<16); }
__device__ __forceinline__ u16 f2bf(float f){
  unsigned x = __float_as_uint(f);
  return (u16)((x + 0x7FFFu + ((x>>16)&1u)) >> 16);   // RNE; inputs finite
}

__device__ __forceinline__ void gll16(const void* g, void* l){
  __builtin_amdgcn_global_load_lds((const __attribute__((address_space(1))) void*)g,
                                   (__attribute__((address_space(3))) void*)l,
                                   16, 0, 0);
}

__device__ __forceinline__ float wsum64(float v){
  #pragma unroll
  for (int o = 32; o > 0; o >>= 1) v += __shfl_xor(v, o, 64);
  return v;
}

// inline dtype detect (prep only): scan x[0:1024] as bf16.
__device__ __forceinline__ int detect_f(const u16* __restrict__ x){
  const int lane = threadIdx.x & 63;
  float mx = 0.f;
  #pragma unroll
  for (int i = 0; i < 16; i++) {
    float v = fabsf(bf2f(x[i*64 + lane]));
    if (!(v < 1e30f)) v = 1e30f;
    mx = fmaxf(mx, v);
  }
  #pragma unroll
  for (int o = 32; o; o >>= 1) mx = fmaxf(mx, __shfl_xor(mx, o, 64));
  return mx < 1e5f;   // 1 = device buffers are bf16
}

__device__ __forceinline__ float ldany(const void* p, size_t i, int f){
  return f ? bf2f(((const u16*)p)[i]) : ((const float*)p)[i];
}

// ---------------------------------------------------------------- prep (fused)
// bid [0,256):    x convert f32->bf16 (skip if bf16)
// bid [256,688):  qkv_w transpose tile (432 tiles)
// bid [688,832):  proj_w transpose tile (144 tiles)
// bid [832,1600): htmm for (b,h): inline 64-col mean, 64x768 matvec, LN+GELU+pos
// bid 1600:       write flag + convert qkv_b -> bf16
// bid 1601:       convert proj_b -> bf16
__global__ __launch_bounds__(256) void prep_kernel(
    const void* __restrict__ xr, const void* __restrict__ w1, const void* __restrict__ w2,
    const void* __restrict__ htw, const void* __restrict__ htb,
    const void* __restrict__ lng, const void* __restrict__ lnb, const void* __restrict__ pos,
    const void* __restrict__ qb_raw, const void* __restrict__ pb_raw,
    u16* __restrict__ xc, u16* __restrict__ o1, u16* __restrict__ o2,
    u16* __restrict__ ht, u16* __restrict__ qbb, u16* __restrict__ pbb,
    int* __restrict__ flagp)
{
  const int tid = threadIdx.x;
  const int f = detect_f((const u16*)xr);
  const int bid = blockIdx.x;
  __shared__ u16 lds[64][66];
  __shared__ float part[4][64];
  __shared__ float msh[64];

  if (bid >= 1600) {                     // ---- flag + bias converts
    if (bid == 1600) {
      if (tid == 0) *flagp = f;
      for (int i = tid; i < NQKV; i += 256) qbb[i] = f2bf(ldany(qb_raw, i, f));
    } else {
      for (int i = tid; i < CDIM; i += 256) pbb[i] = f2bf(ldany(pb_raw, i, f));
    }
    return;
  }
  if (bid < 256) {                       // ---- x convert
    if (f) return;
    const f32x4* in = (const f32x4*)xr;
    const int n4 = XN >> 2;
    for (int i = bid*256 + tid; i < n4; i += 256*256) {
      f32x4 v = in[i];
      u16x4 o;
      #pragma unroll
      for (int j=0;j<4;j++) o[j] = f2bf(v[j]);
      ((u16x4*)xc)[i] = o;
    }
    return;
  }
  if (bid < 832) {                       // ---- weight transposes
    const void* in; u16* out; int N, tx, ty;
    if (bid < 688) { int t = bid-256; in = w1; out = o1; N = NQKV; tx = t % 36; ty = t / 36; }
    else           { int t = bid-688; in = w2; out = o2; N = CDIM; tx = t % 12; ty = t / 12; }
    const int n0 = tx*64, k0 = ty*64;
    const int c = tid & 63, r0 = tid >> 6;
    #pragma unroll
    for (int i=0;i<16;i++) {
      int r = i*4 + r0;
      size_t idx = (size_t)(k0+r)*N + n0 + c;
      lds[r][c] = f ? ((const u16*)in)[idx] : f2bf(((const float*)in)[idx]);
    }
    __syncthreads();
    #pragma unroll
    for (int i=0;i<16;i++) {
      int r = i*4 + r0;
      out[(size_t)(n0+r)*CDIM + k0 + c] = lds[c][r];
    }
    return;
  }

  // ---- htmm: (b,h)
  const int idx = bid - 832;
  const int b = idx / NH, h = idx - b*NH;
  const int c = tid & 63, rg = tid >> 6;
  float s = 0.f;
  for (int n = rg; n < NTOK; n += 4)
    s += ldany(xr, (size_t)(b*NTOK + n)*CDIM + h*HD + c, f);
  part[rg][c] = s;
  __syncthreads();
  if (tid < 64) msh[tid] = (part[0][tid]+part[1][tid]+part[2][tid]+part[3][tid]) * (1.0f/(float)NTOK);
  __syncthreads();

  float v0 = ldany(htb, tid, f), v1 = ldany(htb, tid+256, f), v2 = ldany(htb, tid+512, f);
  for (int d = 0; d < HD; d++) {
    const float md = msh[d];
    const size_t wr = (size_t)d*CDIM;
    v0 += md * ldany(htw, wr + tid, f);
    v1 += md * ldany(htw, wr + tid + 256, f);
    v2 += md * ldany(htw, wr + tid + 512, f);
  }
  const float gam = ldany(lng, tid & 63, f), bet = ldany(lnb, tid & 63, f);
  float vv[3] = {v0, v1, v2};
  #pragma unroll
  for (int ch = 0; ch < 3; ch++) {
    int cc = ch*256 + tid;
    float mu = wsum64(vv[ch]) * (1.0f/(float)HD);
    float dv = vv[ch] - mu;
    float var = wsum64(dv*dv) * (1.0f/(float)HD);
    float y = dv * rsqrtf(var + 1e-5f) * gam + bet;
    float ge = 0.5f * y * (1.0f + erff(y * 0.70710678118654752f));
    float o = ge + ldany(pos, h*CDIM + cc, f);
    ht[((size_t)(b*NH + h))*CDIM + cc] = f2bf(o);
  }
}

// ---------------------------------------------------------------- GEMM
// R21-proven (77µs): flag from memory (uniform SGPR), bf16 bias pointer.
// 128x128 tile, BK=32, 4 waves, ring-5 buffers (80KB), depth-3 prefetch,
// single barrier/iter, counted vmcnt, XOR seg swizzle, m204 XCD remap.
template<int MODE>
__global__ __launch_bounds__(256, 2) void gemm_kernel(
    const u16* __restrict__ A0c, const void* __restrict__ A0r,
    const u16* __restrict__ A1,
    const u16* __restrict__ Bt, const u16* __restrict__ bias,
    u16* __restrict__ qout,
    void* __restrict__ outv, float* __restrict__ csb, const int* __restrict__ flag)
{
  const int tid = threadIdx.x;
  const int lane = tid & 63;
  const int w = tid >> 6;
  const int wm = w >> 1, wn = w & 1;
  const int lr = lane & 15, kg = lane >> 4;

  const int NT = gridDim.x;
  const int nwg = NT * gridDim.y;
  const int orig = blockIdx.y * NT + blockIdx.x;
  const int xcd = orig & 7, sIdx = orig >> 3;
  const int q = nwg >> 3, r = nwg & 7;
  const int wg = ((xcd < r) ? xcd*(q+1) : r*(q+1) + (xcd-r)*q) + sIdx;
  const int tm = wg / NT, tn = wg - tm*NT;

  __shared__ __align__(16) u16 As[5][4096];   // [buf][row*32 + seg*8 + e]
  __shared__ __align__(16) u16 Bs[5][4096];

  const int f = *flag;
  const u16* A0 = (MODE == 0) ? (f ? (const u16*)A0r : A0c) : A0c;

  f32x4 acc[4][4];
  #pragma unroll
  for (int i=0;i<4;i++)
    #pragma unroll
    for (int j=0;j<4;j++) acc[i][j] = (f32x4){0.f,0.f,0.f,0.f};

  const u16* garow[2];
  const u16* gbrow[2];
  #pragma unroll
  for (int i=0;i<2;i++){
    int row = (i*4 + w)*16 + (lane >> 2);
    int rr = tm*128 + row; if (rr > GM-1) rr = GM-1;
    if (MODE == 0) {
      int bb = rr / TT; int t = rr - bb*TT;
      garow[i] = (t < NTOK) ? (A0 + (size_t)(bb*NTOK + t)*CDIM)
                            : (A1 + (size_t)(bb*NH + (t - NTOK))*CDIM);
    } else {
      garow[i] = A0 + (size_t)rr*CDIM;
    }
    gbrow[i] = Bt + (size_t)(tn*128 + row)*CDIM;
  }
  const int gseg = (lane & 3) ^ ((lane >> 3) & 3);   // = seg ^ ((row>>1)&3)

#define STAGE(kt_, bf_) do { \
    const int ko_ = (kt_)*32 + gseg*8; \
    gll16(garow[0] + ko_, (void*)&As[bf_][(0*4+w)*512]); \
    gll16(garow[1] + ko_, (void*)&As[bf_][(1*4+w)*512]); \
    gll16(gbrow[0] + ko_, (void*)&Bs[bf_][(0*4+w)*512]); \
    gll16(gbrow[1] + ko_, (void*)&Bs[bf_][(1*4+w)*512]); \
  } while(0)

  STAGE(0, 0);
  STAGE(1, 1);
  STAGE(2, 2);

  const int spA = kg ^ ((lr >> 1) & 3);   // read-side swizzled segment

  #pragma unroll
  for (int kt = 0; kt < 24; kt++) {
    const int cb = kt % 5;
    if (kt < 21) {
      STAGE(kt+3, (kt+3)%5);
      asm volatile("s_waitcnt vmcnt(12)" ::: "memory");   // stage kt drained
    } else if (kt == 21) {
      asm volatile("s_waitcnt vmcnt(8)" ::: "memory");
    } else if (kt == 22) {
      asm volatile("s_waitcnt vmcnt(4)" ::: "memory");
    } else {
      asm volatile("s_waitcnt vmcnt(0)" ::: "memory");
    }
    __builtin_amdgcn_s_barrier();     // single barrier/iter (ring-5 WAR proof)

    bf16x8 av[4], bv[4];
    #pragma unroll
    for (int mi=0; mi<4; mi++)
      av[mi] = *(const bf16x8*)&As[cb][(wm*64+mi*16+lr)*32 + spA*8];
    #pragma unroll
    for (int ni=0; ni<4; ni++)
      bv[ni] = *(const bf16x8*)&Bs[cb][(wn*64+ni*16+lr)*32 + spA*8];
    #pragma unroll
    for (int mi=0; mi<4; mi++)
      #pragma unroll
      for (int ni=0; ni<4; ni++)
        acc[mi][ni] = __builtin_amdgcn_mfma_f32_16x16x32_bf16(av[mi], bv[ni], acc[mi][ni], 0,0,0);
  }
#undef STAGE

  #pragma unroll
  for (int mi=0; mi<4; mi++){
    const int rb = tm*128 + wm*64 + mi*16 + kg*4;
    #pragma unroll
    for (int ni=0; ni<4; ni++){
      const int c = tn*128 + wn*64 + ni*16 + lr;
      const float bs = bf2f(bias[c]);
      if (MODE == 0) {
        #pragma unroll
        for (int j=0;j<4;j++){
          int rr = rb + j;
          if (rr < GM) qout[(size_t)rr*NQKV + c] = f2bf(acc[mi][ni][j] + bs);
        }
      } else {
        #pragma unroll
        for (int j=0;j<4;j++){
          int rr = rb + j;
          if (rr < GM) {
            int bb = rr / TT; int t = rr - bb*TT;
            float v = acc[mi][ni][j] + bs;
            if (t >= 1 && t < NTOK) {
              size_t oi = ((size_t)(bb*NTOK + t))*CDIM + c;
              if (f) ((u16*)outv)[oi] = f2bf(v);
              else   ((float*)outv)[oi] = v;
            } else {
              int idx = (t == 0) ? 0 : (t - NTOK + 1);   // 0, 1..12
              csb[((size_t)(bb*13 + idx))*CDIM + c] = v;
            }
          }
        }
      }
    }
  }
}

// ---------------------------------------------------------------- attention v3 (R22-proven)
// One block (4 waves, 256 thr) per (b,h). K staged [224][72]; V staged
// transposed [64][232] (zero-pad); one __syncthreads. Per wave: q-chunks
// ck = w, w+4, ...; in-register softmax (swapped QK^T); per-wave 16x32
// P slot written/consumed per ks (wave-local lgkmcnt ordering). LDS 66KB.
__global__ __launch_bounds__(256) void attn_kernel(
    const u16* __restrict__ qkvo, u16* __restrict__ ob)
{
  __shared__ __align__(16) u16 Kl[224*72];      // 32256 B
  __shared__ __align__(16) u16 Vt[64*232];      // 29696 B
  __shared__ __align__(16) u16 P[4][16*32];     //  4096 B
  const int tid = threadIdx.x;
  const int lane = tid & 63;
  const int w = tid >> 6;
  const int lr = lane & 15, kg = lane >> 4;

  const int bh = blockIdx.x;
  const int b = bh / NH, h = bh - b*NH;

  const u16* qg   = qkvo + (size_t)(b*TT)*NQKV + h*64;
  const u16* kgp  = qg + CDIM;
  const u16* vsrc = qg + 2*CDIM;

  for (int s = tid; s < 224*8; s += 256) {
    int kc = s >> 3, seg = s & 7;
    uint4 val = make_uint4(0,0,0,0);
    if (kc < TT) val = *(const uint4*)&kgp[(size_t)kc*NQKV + seg*8];
    *(uint4*)&Kl[kc*72 + seg*8] = val;
  }
  for (int s = tid; s < TT*64; s += 256) {
    int t = s >> 6, d = s & 63;
    Vt[d*232 + t] = vsrc[(size_t)t*NQKV + d];
  }
  for (int s = tid; s < 64*(VTP-TT); s += 256) {
    int d = s / (VTP-TT), i = s - d*(VTP-TT);
    Vt[d*232 + TT + i] = 0;
  }
  __syncthreads();

  u16* Pw = &P[w][0];
  for (int ck = w; ck < 14; ck += 4) {
    const int q0 = ck*16;
    int qrow = q0 + lr; if (qrow > TT-1) qrow = TT-1;
    const bf16x8 qf0 = *(const bf16x8*)&qg[(size_t)qrow*NQKV + kg*8];
    const bf16x8 qf1 = *(const bf16x8*)&qg[(size_t)qrow*NQKV + 32 + kg*8];

    f32x4 sv[14];
    #pragma unroll
    for (int kt = 0; kt < 14; kt++) {
      bf16x8 kf0 = *(const bf16x8*)&Kl[(kt*16+lr)*72 + kg*8];
      bf16x8 kf1 = *(const bf16x8*)&Kl[(kt*16+lr)*72 + 32 + kg*8];
      f32x4 sa = {0.f,0.f,0.f,0.f};
      sa = __builtin_amdgcn_mfma_f32_16x16x32_bf16(kf0, qf0, sa, 0,0,0);
      sa = __builtin_amdgcn_mfma_f32_16x16x32_bf16(kf1, qf1, sa, 0,0,0);
      sv[kt] = sa;
    }

    float m = -3.0e38f;
    #pragma unroll
    for (int kt = 0; kt < 13; kt++)
      #pragma unroll
      for (int j=0;j<4;j++){ sv[kt][j] *= 0.125f; m = fmaxf(m, sv[kt][j]); }
    #pragma unroll
    for (int j=0;j<4;j++){
      sv[13][j] *= 0.125f;
      if (208 + kg*4 + j < TT) m = fmaxf(m, sv[13][j]);
    }
    m = fmaxf(m, __shfl_xor(m, 16, 64));
    m = fmaxf(m, __shfl_xor(m, 32, 64));

    float ssum = 0.f;
    #pragma unroll
    for (int kt = 0; kt < 13; kt++)
      #pragma unroll
      for (int j=0;j<4;j++){ float e = __expf(sv[kt][j] - m); sv[kt][j] = e; ssum += e; }
    #pragma unroll
    for (int j=0;j<4;j++){
      float e = (208 + kg*4 + j < TT) ? __expf(sv[13][j] - m) : 0.f;
      sv[13][j] = e; ssum += e;
    }
    ssum += __shfl_xor(ssum, 16, 64);
    ssum += __shfl_xor(ssum, 32, 64);
    const float inv = 1.0f / ssum;

    f32x4 acc[4];
    #pragma unroll
    for (int dt=0; dt<4; dt++) acc[dt] = (f32x4){0.f,0.f,0.f,0.f};
    #pragma unroll
    for (int ks = 0; ks < 7; ks++) {
      u16x4 pk0, pk1;
      #pragma unroll
      for (int j=0;j<4;j++){
        pk0[j] = f2bf(sv[2*ks  ][j] * inv);
        pk1[j] = f2bf(sv[2*ks+1][j] * inv);
      }
      *(u16x4*)&Pw[lr*32      + kg*4] = pk0;
      *(u16x4*)&Pw[lr*32 + 16 + kg*4] = pk1;
      bf16x8 pf = *(const bf16x8*)&Pw[lr*32 + kg*8];
      #pragma unroll
      for (int dt = 0; dt < 4; dt++) {
        bf16x8 vf = *(const bf16x8*)&Vt[(dt*16+lr)*232 + ks*32 + kg*8];
        acc[dt] = __builtin_amdgcn_mfma_f32_16x16x32_bf16(pf, vf, acc[dt], 0,0,0);
      }
    }

    #pragma unroll
    for (int dt = 0; dt < 4; dt++)
      #pragma unroll
      for (int j = 0; j < 4; j++) {
        int tq = q0 + kg*4 + j;
        if (tq < TT)
          ob[((size_t)(b*TT + tq))*CDIM + h*HD + dt*16 + lr] = f2bf(acc[dt][j]);
      }
  }
}

// ---------------------------------------------------------------- final2 (cls row)
__global__ __launch_bounds__(256) void final2_kernel(
    const float* __restrict__ csb, void* __restrict__ outv, const int* __restrict__ flag)
{
  const int f = *flag;
  int i = blockIdx.x*256 + threadIdx.x;
  if (i >= BATCH*CDIM) return;
  int b = i / CDIM, c = i - b*CDIM;
  const float* p = csb + (size_t)b*13*CDIM + c;
  float s = 0.f;
  #pragma unroll
  for (int j = 1; j <= 12; j++) s += p[(size_t)j*CDIM];
  float v = p[0] + s * (1.0f/12.0f);
  size_t oi = ((size_t)b*NTOK)*CDIM + c;
  if (f) ((u16*)outv)[oi] = f2bf(v);
  else   ((float*)outv)[oi] = v;
}

// ---------------------------------------------------------------- launch
extern "C" void kernel_launch(void* const* d_in, const int* in_sizes, int n_in,
                              void* d_out, int out_size, void* d_ws, size_t ws_size,
                              hipStream_t stream)
{
  char* ws = (char*)d_ws;
  size_t off = 0;
  auto alloc = [&](size_t bytes)->void* {
    void* p = ws + off; off += (bytes + 255) & ~(size_t)255; return p;
  };

  int* flag  = (int*)alloc(256);
  u16* qbb   = (u16*)alloc((size_t)NQKV*2);               // bf16 qkv_b
  u16* pbb   = (u16*)alloc((size_t)CDIM*2);               // bf16 proj_b
  u16* xconv = (u16*)alloc((size_t)XN*2);                 // bf16 x (19.4MB)
  u16* qkvT  = (u16*)alloc((size_t)3*CDIM*CDIM*2);        // 2304 x 768 (3.5MB)
  u16* projT = (u16*)alloc((size_t)CDIM*CDIM*2);          // 768 x 768
  u16* htb_  = (u16*)alloc((size_t)BATCH*NH*CDIM*2);      // (B*H) x 768
  u16* qkvo  = (u16*)alloc((size_t)GM*NQKV*2);            // (B*T) x 2304
  float* csb = (float*)alloc((size_t)BATCH*13*CDIM*4);    // cls side buffer
  // ao (20.55MB) aliases xconv+qkvT (22.9MB): both dead after gemm<0>.
  u16* ao    = xconv;

  prep_kernel<<<1602, 256, 0, stream>>>(
      d_in[0], d_in[1], d_in[3], d_in[5], d_in[6], d_in[7], d_in[8], d_in[9],
      d_in[2], d_in[4],
      xconv, qkvT, projT, htb_, qbb, pbb, flag);
  gemm_kernel<0><<<dim3(NQKV/128, (GM+127)/128), 256, 0, stream>>>(
      xconv, d_in[0], htb_, qkvT, qbb, qkvo, nullptr, nullptr, flag);
  attn_kernel<<<BATCH*NH, 256, 0, stream>>>(qkvo, ao);
  gemm_kernel<1><<<dim3(CDIM/128, (GM+127)/128), 256, 0, stream>>>(
      ao, nullptr, nullptr, projT, pbb, nullptr, d_out, csb, flag);
  final2_kernel<<<(BATCH*CDIM+255)/256, 256, 0, stream>>>(csb, d_out, flag);
}